// Round 2
// baseline (5593.380 us; speedup 1.0000x reference)
//
#include <hip/hip_runtime.h>
#include <hip/hip_bf16.h>
#include <cstddef>

#define B_  4
#define N_  4096
#define M_  2048
#define K_  32      // NSAMPLE
// padded t in 1..8 -> anchor frame s = t-1; neighbor orig frame = clamp(s+j-1, 0, 7)

// IEEE mul/add without fma contraction: the XLA reference emits sub/mul then
// reduce-add (no fused fma across the reduce combiner). FPS argmax and ball
// query d2<r^2 are DISCRETE selectors — contraction differences cascade.
__device__ __forceinline__ float sq3_rn(float dx, float dy, float dz) {
    return __fadd_rn(__fadd_rn(__fmul_rn(dx, dx), __fmul_rn(dy, dy)), __fmul_rn(dz, dz));
}

// ---------------------------------------------------------------------------
// FPS: one block per (b, s). 16 points/thread register-resident; coords also
// in LDS to fetch the chosen point. idx[it] = last BEFORE update (jax scan);
// argmax first-index tie-break; dist init 1e10.
// ---------------------------------------------------------------------------
__global__ __launch_bounds__(256) void fps_kernel(
    const float* __restrict__ xyzs,   // [B,8,4096,3]
    float* __restrict__ out_xyz)      // [B,8,2048,3]
{
    const int blk = blockIdx.x;       // b*8 + s
    const int tid = threadIdx.x;
    const float* fr = xyzs + (size_t)blk * (N_ * 3);
    float* ox = out_xyz + (size_t)blk * (M_ * 3);

    __shared__ float sx[N_], sy[N_], sz[N_];
    __shared__ float rv[4];
    __shared__ int   ri[4];
    __shared__ int   s_last;

    float px[16], py[16], pz[16], dist[16];
#pragma unroll
    for (int u = 0; u < 16; ++u) {
        const int p = u * 256 + tid;
        const float x = fr[p*3+0], y = fr[p*3+1], z = fr[p*3+2];
        px[u] = x; py[u] = y; pz[u] = z; dist[u] = 1e10f;
        sx[p] = x; sy[p] = y; sz[p] = z;
    }
    __syncthreads();

    const int lane = tid & 63, wave = tid >> 6;
    int last = 0;
    for (int it = 0; it < M_; ++it) {
        const float lx = sx[last], ly = sy[last], lz = sz[last];
        if (tid == 0) { ox[it*3+0] = lx; ox[it*3+1] = ly; ox[it*3+2] = lz; }

        float bv = -1.0f; int bi = 0;
#pragma unroll
        for (int u = 0; u < 16; ++u) {
            const float d = sq3_rn(px[u]-lx, py[u]-ly, pz[u]-lz);
            const float nd = fminf(dist[u], d);
            dist[u] = nd;
            const int p = u * 256 + tid;
            if (nd > bv) { bv = nd; bi = p; }   // u ascending => p ascending; ties keep first
        }
#pragma unroll
        for (int off = 32; off; off >>= 1) {
            const float ov = __shfl_down(bv, off);
            const int   oi = __shfl_down(bi, off);
            if (ov > bv || (ov == bv && oi < bi)) { bv = ov; bi = oi; }
        }
        if (lane == 0) { rv[wave] = bv; ri[wave] = bi; }
        __syncthreads();
        if (tid == 0) {
            float v = rv[0]; int idx = ri[0];
#pragma unroll
            for (int w = 1; w < 4; ++w)
                if (rv[w] > v || (rv[w] == v && ri[w] < idx)) { v = rv[w]; idx = ri[w]; }
            s_last = idx;
        }
        __syncthreads();
        last = s_last;
    }
}

// ---------------------------------------------------------------------------
// Fused ball-query + gather + MLP(64) + MLP(128) + maxpool(32) + temporal
// conv(256). Block = (bt, group of 4 anchors), 256 threads, j=0..2 in-block.
//   BQ     : wave wa scans frame for anchor wa -> sbidx[4][32] in LDS
//   phase A: 2 threads/point -> h1T[anchor][k][q] (ReLU'd layer-1)
//   phase B: per-anchor GEMM C[128oc][32q]; lane microtile 16oc x 4q from
//            bank-swizzled ws1T (conflict-free) + h1T; shfl_xor maxpool
//   phase C: thread<->oc, Wt rows direct (L2-resident), st += relu(Wt @ hmax)
// ---------------------------------------------------------------------------
__global__ __launch_bounds__(256, 2) void mlp_kernel(
    const float* __restrict__ xyzs,      // [B,8,4096,3]
    const float* __restrict__ feats,     // [B,8,3,4096]
    const float* __restrict__ Ws0,       // [64,6]
    const float* __restrict__ Ws1,       // [128,64]
    const float* __restrict__ Wt,        // [3,256,128]
    const float* __restrict__ anchors,   // [B,8,2048,3] (fps output)
    float* __restrict__ out_feat)        // [B,8,256,2048]
{
    const int blk = blockIdx.x;
    const int mb  = blk & 511;           // 4-anchor group
    const int bt  = blk >> 9;
    const int b = bt >> 3, t = bt & 7;
    const int tid = threadIdx.x;
    const int lane = tid & 63, wa = tid >> 6;

    // ws1T: element (k, oc) at k*132 + ((oc>>2)&3)*32 + (oc>>4)*4 + (oc&3).
    // Phase-B instruction (k,c fixed) reads og*4..+3 for og=0..7 -> 8 disjoint
    // bank quads -> conflict-free. Row stride 132 keeps 16B alignment.
    __shared__ float ws1T[64 * 132];         // 33.8 KB
    __shared__ float h1T[4][64][32];         // 32 KB
    __shared__ float hmax[4][128];           // 2 KB
    __shared__ float w0s[64][8];             // 2 KB (cols 6,7 unused)
    __shared__ float anc[4][3];
    __shared__ unsigned short sbidx[4][32];  // ball-query result per anchor

    // ---- one-time staging ----
    for (int i = tid; i < 384; i += 256) w0s[i / 6][i % 6] = Ws0[i];
    {
        const float4* wp4 = (const float4*)Ws1;     // 2048 float4
#pragma unroll
        for (int u = 0; u < 8; ++u) {
            const int f4 = u * 256 + tid;
            const float4 v = wp4[f4];
            const int oc = f4 >> 4;                 // Ws1 row
            const int k0 = (f4 & 15) * 4;           // Ws1 col
            const int pos = ((oc >> 2) & 3) * 32 + (oc >> 4) * 4 + (oc & 3);
            ws1T[(k0 + 0) * 132 + pos] = v.x;
            ws1T[(k0 + 1) * 132 + pos] = v.y;
            ws1T[(k0 + 2) * 132 + pos] = v.z;
            ws1T[(k0 + 3) * 132 + pos] = v.w;
        }
    }
    if (tid < 12) anc[tid / 3][tid % 3] =
        anchors[((size_t)bt * M_ + mb * 4 + tid / 3) * 3 + tid % 3];
    __syncthreads();

    const int p  = tid & 127;            // phase-A point id (4 anchors x 32 nb)
    const int oh = tid >> 7;             // phase-A o-half
    const int pa = p >> 5, nb = p & 31;
    const int og = lane >> 3;            // phase-B oc group (16 oc)
    const int qg = lane & 7;             // phase-B q group (4 q)

    float st0 = 0.f, st1 = 0.f, st2 = 0.f, st3 = 0.f;

    for (int j = 0; j < 3; ++j) {
        int fi = t + j - 1; fi = fi < 0 ? 0 : (fi > 7 ? 7 : fi);
        const float* fr = xyzs + (size_t)(b * 8 + fi) * (N_ * 3);

        // ---- ball query: wave wa <-> anchor wa, first-32 ascending ----
        {
            const float ax = anc[wa][0], ay = anc[wa][1], az = anc[wa][2];
            int cnt = 0, first = 0;
            for (int c = 0; c < 64; ++c) {
                const int n = c * 64 + lane;
                const float d2 = sq3_rn(fr[n*3+0]-ax, fr[n*3+1]-ay, fr[n*3+2]-az);
                const bool hit = d2 < 0.25f;
                const unsigned long long mask = __ballot(hit);
                if (mask) {
                    if (cnt == 0) first = c * 64 + __builtin_ctzll(mask);
                    if (hit) {
                        const int pos = cnt + (int)__popcll(mask & ((1ull << lane) - 1ull));
                        if (pos < K_) sbidx[wa][pos] = (unsigned short)n;
                    }
                    cnt += (int)__popcll(mask);
                    if (cnt >= K_) break;
                }
            }
            if (lane < K_ && lane >= cnt) sbidx[wa][lane] = (unsigned short)(cnt ? first : 0);
        }
        __syncthreads();

        // ---- phase A: gather + layer1 -> h1T[pa][k][nb] ----
        {
            const int n = sbidx[pa][nb];
            const float* nx = xyzs + ((size_t)(b*8 + fi) * N_ + n) * 3;
            const float X = nx[0], Y = nx[1], Z = nx[2];
            const float* fp = feats + (size_t)(b*8 + fi) * (3 * N_) + n;
            const float f0 = fp[0], f1 = fp[N_], f2 = fp[2 * N_];
            const float s0 = X - anc[pa][0], s1 = Y - anc[pa][1], s2 = Z - anc[pa][2];
#pragma unroll
            for (int o4 = 0; o4 < 8; ++o4) {
#pragma unroll
                for (int oo = 0; oo < 4; ++oo) {
                    const int o = oh * 32 + o4 * 4 + oo;
                    const float4 A  = *(const float4*)&w0s[o][0];
                    const float4 Bv = *(const float4*)&w0s[o][4];  // .z/.w unused
                    const float r = A.x*s0 + A.y*s1 + A.z*s2 + A.w*f0 + Bv.x*f1 + Bv.y*f2;
                    h1T[pa][o][nb] = fmaxf(r, 0.f);
                }
            }
        }
        __syncthreads();

        // ---- phase B: wave-per-anchor GEMM + relu + maxpool ----
        {
            float4 acc4[16];   // acc4[c*4+i] = C[og*16+c*4+i][qg*4 .. +3]
#pragma unroll
            for (int i = 0; i < 16; ++i) acc4[i] = make_float4(0.f, 0.f, 0.f, 0.f);
            const float* wrow = ws1T + og * 4;
            const float* hrow = &h1T[wa][0][qg * 4];
#define ACC4(base, wv) \
    acc4[base+0].x += wv.x*h.x; acc4[base+0].y += wv.x*h.y; acc4[base+0].z += wv.x*h.z; acc4[base+0].w += wv.x*h.w; \
    acc4[base+1].x += wv.y*h.x; acc4[base+1].y += wv.y*h.y; acc4[base+1].z += wv.y*h.z; acc4[base+1].w += wv.y*h.w; \
    acc4[base+2].x += wv.z*h.x; acc4[base+2].y += wv.z*h.y; acc4[base+2].z += wv.z*h.z; acc4[base+2].w += wv.z*h.w; \
    acc4[base+3].x += wv.w*h.x; acc4[base+3].y += wv.w*h.y; acc4[base+3].z += wv.w*h.z; acc4[base+3].w += wv.w*h.w;
#pragma unroll 8
            for (int k = 0; k < 64; ++k) {
                const float4 h  = *(const float4*)(hrow + k * 32);
                const float4 w0 = *(const float4*)(wrow + k * 132);
                const float4 w1 = *(const float4*)(wrow + k * 132 + 32);
                const float4 w2 = *(const float4*)(wrow + k * 132 + 64);
                const float4 w3 = *(const float4*)(wrow + k * 132 + 96);
                ACC4(0, w0) ACC4(4, w1) ACC4(8, w2) ACC4(12, w3)
            }
#undef ACC4
#pragma unroll
            for (int i = 0; i < 16; ++i) {
                float m = fmaxf(fmaxf(acc4[i].x, acc4[i].y), fmaxf(acc4[i].z, acc4[i].w));
                m = fmaxf(m, __shfl_xor(m, 1));
                m = fmaxf(m, __shfl_xor(m, 2));
                m = fmaxf(m, __shfl_xor(m, 4));
                if (qg == 0) hmax[wa][og * 16 + i] = fmaxf(m, 0.f);
            }
        }
        __syncthreads();

        // ---- phase C: thread<->oc, st += relu(Wt[j][oc] . hmax[a]) ----
        {
            const float4* wr = (const float4*)(Wt + ((size_t)j << 15) + ((size_t)tid << 7));
            float c0 = 0.f, c1 = 0.f, c2 = 0.f, c3 = 0.f;
#pragma unroll 8
            for (int k4 = 0; k4 < 32; ++k4) {
                const float4 w  = wr[k4];
                const float4 m0 = *(const float4*)&hmax[0][k4 * 4];
                const float4 m1 = *(const float4*)&hmax[1][k4 * 4];
                const float4 m2 = *(const float4*)&hmax[2][k4 * 4];
                const float4 m3 = *(const float4*)&hmax[3][k4 * 4];
                c0 += w.x*m0.x + w.y*m0.y + w.z*m0.z + w.w*m0.w;
                c1 += w.x*m1.x + w.y*m1.y + w.z*m1.z + w.w*m1.w;
                c2 += w.x*m2.x + w.y*m2.y + w.z*m2.z + w.w*m2.w;
                c3 += w.x*m3.x + w.y*m3.y + w.z*m3.z + w.w*m3.w;
            }
            st0 += fmaxf(c0, 0.f);
            st1 += fmaxf(c1, 0.f);
            st2 += fmaxf(c2, 0.f);
            st3 += fmaxf(c3, 0.f);
        }
        // no sync: next BQ writes only sbidx (readers done two syncs ago);
        // hmax rewritten only after next post-A sync.
    }

    // thread tid owns output row oc=tid, cols mb*4..+3 -> one float4 store
    *(float4*)(out_feat + ((size_t)bt * 256 + tid) * M_ + mb * 4) =
        make_float4(st0, st1, st2, st3);
}

// ---------------------------------------------------------------------------
extern "C" void kernel_launch(void* const* d_in, const int* in_sizes, int n_in,
                              void* d_out, int out_size, void* d_ws, size_t ws_size,
                              hipStream_t stream) {
    const float* xyzs  = (const float*)d_in[0];   // [4,8,4096,3]
    const float* feats = (const float*)d_in[1];   // [4,8,3,4096]
    const float* Ws0   = (const float*)d_in[2];   // [64,6]
    const float* Ws1   = (const float*)d_in[3];   // [128,64]
    const float* Wt    = (const float*)d_in[4];   // [3,256,128]

    float* out_xyz  = (float*)d_out;              // 4*8*2048*3 = 196608 floats
    float* out_feat = out_xyz + (size_t)B_ * 8 * M_ * 3;

    (void)d_ws; (void)ws_size;  // workspace-free by design

    fps_kernel<<<B_ * 8, 256, 0, stream>>>(xyzs, out_xyz);
    mlp_kernel<<<B_ * 8 * (M_ / 4), 256, 0, stream>>>(xyzs, feats, Ws0, Ws1, Wt,
                                                      out_xyz, out_feat);
}

// Round 3
// 4412.614 us; speedup vs baseline: 1.2676x; 1.2676x over previous
//
#include <hip/hip_runtime.h>
#include <hip/hip_bf16.h>
#include <cstddef>

#define B_  4
#define N_  4096
#define M_  2048
#define K_  32      // NSAMPLE
// padded t in 1..8 -> anchor frame s = t-1; neighbor orig frame = clamp(s+j-1, 0, 7)

// IEEE mul/add without fma contraction: FPS argmax and ball-query d2<r^2 are
// DISCRETE selectors — contraction differences cascade. This exact form PASSED
// round 2 (absmax 9.8e-4). Do not change.
__device__ __forceinline__ float sq3_rn(float dx, float dy, float dz) {
    return __fadd_rn(__fadd_rn(__fmul_rn(dx, dx), __fmul_rn(dy, dy)), __fmul_rn(dz, dz));
}

// ---------------------------------------------------------------------------
// FPS: one block per (b, s), 512 threads, 8 pts/thread register-resident.
// Per iteration: pack (dist_bits<<32)|~idx into u64 -> single unsigned max
// gives argmax with first-index tie-break; 6-step shfl_xor butterfly; ONE
// barrier/iter via parity double-buffered per-wave slots; every thread
// redundantly reduces the 8 wave results (no tid0 funnel, no 2nd barrier).
// ---------------------------------------------------------------------------
__global__ __launch_bounds__(512) void fps_kernel(
    const float* __restrict__ xyzs,   // [B,8,4096,3]
    float* __restrict__ out_xyz)      // [B,8,2048,3]
{
    const int blk = blockIdx.x;       // b*8 + s
    const int tid = threadIdx.x;
    const float* fr = xyzs + (size_t)blk * (N_ * 3);
    float* ox = out_xyz + (size_t)blk * (M_ * 3);

    __shared__ float sx[N_], sy[N_], sz[N_];
    __shared__ unsigned long long sred[2][8];

    float px[8], py[8], pz[8], dist[8];
#pragma unroll
    for (int u = 0; u < 8; ++u) {
        const int p = u * 512 + tid;
        const float x = fr[p*3+0], y = fr[p*3+1], z = fr[p*3+2];
        px[u] = x; py[u] = y; pz[u] = z; dist[u] = 1e10f;
        sx[p] = x; sy[p] = y; sz[p] = z;
    }
    __syncthreads();

    const int lane = tid & 63, wave = tid >> 6;
    int last = 0;
    for (int it = 0; it < M_; ++it) {
        const float lx = sx[last], ly = sy[last], lz = sz[last];
        if (tid == 0) { ox[it*3+0] = lx; ox[it*3+1] = ly; ox[it*3+2] = lz; }

        unsigned long long best = 0ull;
#pragma unroll
        for (int u = 0; u < 8; ++u) {
            const float d = sq3_rn(px[u]-lx, py[u]-ly, pz[u]-lz);
            const float nd = fminf(dist[u], d);
            dist[u] = nd;
            const unsigned long long pk =
                ((unsigned long long)__float_as_uint(nd) << 32) |
                (unsigned)(~(u * 512 + tid));
            best = pk > best ? pk : best;
        }
#pragma unroll
        for (int off = 32; off; off >>= 1) {
            const unsigned long long o = __shfl_xor(best, off);
            best = o > best ? o : best;
        }
        if (lane == 0) sred[it & 1][wave] = best;
        __syncthreads();
        const unsigned long long* sr = sred[it & 1];
        unsigned long long b = sr[0];
#pragma unroll
        for (int w = 1; w < 8; ++w) { const unsigned long long o = sr[w]; b = o > b ? o : b; }
        last = (int)((~(unsigned)b) & (N_ - 1));
    }
}

// ---------------------------------------------------------------------------
// Fused ball-query + gather + MLP(64) + MLP(128) + maxpool(32) + temporal
// conv(256). Block = (bt, 4 anchors), 256 threads, j=0..2 in-block.
//   BQ     : wave wa scans frame for anchor wa -> sbidx[4][32]
//   phase A: 2 threads/point -> h1T[anchor][k][q]
//   phase B: per-anchor GEMM C[128oc][32q]; lane microtile 8oc x 8q
//            (og=lane>>2 16 groups, qg=lane&3 4 groups) -> 0.5 B/FLOP LDS;
//            ws1T bank-interleaved (2-way max = free); maxpool via 2 shfl_xor
//   phase C: thread<->oc, Wt rows direct (L2-resident)
// ---------------------------------------------------------------------------
__global__ __launch_bounds__(256, 2) void mlp_kernel(
    const float* __restrict__ xyzs,      // [B,8,4096,3]
    const float* __restrict__ feats,     // [B,8,3,4096]
    const float* __restrict__ Ws0,       // [64,6]
    const float* __restrict__ Ws1,       // [128,64]
    const float* __restrict__ Wt,        // [3,256,128]
    const float* __restrict__ anchors,   // [B,8,2048,3] (fps output)
    float* __restrict__ out_feat)        // [B,8,256,2048]
{
    const int blk = blockIdx.x;
    const int mb  = blk & 511;           // 4-anchor group
    const int bt  = blk >> 9;
    const int b = bt >> 3, t = bt & 7;
    const int tid = threadIdx.x;
    const int lane = tid & 63, wa = tid >> 6;

    // ws1T: float4 chunk (k, og, cr) at k*128 + og*4 + cr*64 holding
    // oc = og*8 + cr*4 + i. Phase-B read (k, cr fixed): 16 og-addresses ->
    // bank-quads (og + 16cr) mod 8 -> exactly 2-way (free), qg broadcast.
    __shared__ float ws1T[64 * 128];         // 32 KB
    __shared__ float h1T[4][64][32];         // 32 KB
    __shared__ float hmax[4][128];           // 2 KB
    __shared__ float w0s[64][8];             // 2 KB (cols 6,7 unused)
    __shared__ float anc[4][3];
    __shared__ unsigned short sbidx[4][32];

    // ---- one-time staging ----
    for (int i = tid; i < 384; i += 256) w0s[i / 6][i % 6] = Ws0[i];
    {
        const float4* wp4 = (const float4*)Ws1;     // 2048 float4
#pragma unroll
        for (int u = 0; u < 8; ++u) {
            const int f4 = u * 256 + tid;
            const float4 v = wp4[f4];
            const int oc = f4 >> 4;                 // Ws1 row
            const int k0 = (f4 & 15) * 4;           // Ws1 col
            const int base = (oc >> 3) * 4 + ((oc >> 2) & 1) * 64 + (oc & 3);
            ws1T[(k0 + 0) * 128 + base] = v.x;
            ws1T[(k0 + 1) * 128 + base] = v.y;
            ws1T[(k0 + 2) * 128 + base] = v.z;
            ws1T[(k0 + 3) * 128 + base] = v.w;
        }
    }
    if (tid < 12) anc[tid / 3][tid % 3] =
        anchors[((size_t)bt * M_ + mb * 4 + tid / 3) * 3 + tid % 3];
    __syncthreads();

    const int p  = tid & 127;            // phase-A point id (4 anchors x 32 nb)
    const int oh = tid >> 7;             // phase-A o-half
    const int pa = p >> 5, nb = p & 31;
    const int og = lane >> 2;            // phase-B oc group (8 oc)
    const int qg = lane & 3;             // phase-B q group (8 q)

    float st0 = 0.f, st1 = 0.f, st2 = 0.f, st3 = 0.f;

    for (int j = 0; j < 3; ++j) {
        int fi = t + j - 1; fi = fi < 0 ? 0 : (fi > 7 ? 7 : fi);
        const float* fr = xyzs + (size_t)(b * 8 + fi) * (N_ * 3);

        // ---- ball query: wave wa <-> anchor wa, first-32 ascending ----
        {
            const float ax = anc[wa][0], ay = anc[wa][1], az = anc[wa][2];
            int cnt = 0, first = 0;
            for (int c = 0; c < 64; ++c) {
                const int n = c * 64 + lane;
                const float d2 = sq3_rn(fr[n*3+0]-ax, fr[n*3+1]-ay, fr[n*3+2]-az);
                const bool hit = d2 < 0.25f;
                const unsigned long long mask = __ballot(hit);
                if (mask) {
                    if (cnt == 0) first = c * 64 + __builtin_ctzll(mask);
                    if (hit) {
                        const int pos = cnt + (int)__popcll(mask & ((1ull << lane) - 1ull));
                        if (pos < K_) sbidx[wa][pos] = (unsigned short)n;
                    }
                    cnt += (int)__popcll(mask);
                    if (cnt >= K_) break;
                }
            }
            if (lane < K_ && lane >= cnt) sbidx[wa][lane] = (unsigned short)(cnt ? first : 0);
        }
        __syncthreads();

        // ---- phase A: gather + layer1 -> h1T[pa][k][nb] ----
        {
            const int n = sbidx[pa][nb];
            const float* nx = xyzs + ((size_t)(b*8 + fi) * N_ + n) * 3;
            const float X = nx[0], Y = nx[1], Z = nx[2];
            const float* fp = feats + (size_t)(b*8 + fi) * (3 * N_) + n;
            const float f0 = fp[0], f1 = fp[N_], f2 = fp[2 * N_];
            const float s0 = X - anc[pa][0], s1 = Y - anc[pa][1], s2 = Z - anc[pa][2];
#pragma unroll
            for (int o4 = 0; o4 < 8; ++o4) {
#pragma unroll
                for (int oo = 0; oo < 4; ++oo) {
                    const int o = oh * 32 + o4 * 4 + oo;
                    const float4 A  = *(const float4*)&w0s[o][0];
                    const float4 Bv = *(const float4*)&w0s[o][4];  // .z/.w unused
                    const float r = A.x*s0 + A.y*s1 + A.z*s2 + A.w*f0 + Bv.x*f1 + Bv.y*f2;
                    h1T[pa][o][nb] = fmaxf(r, 0.f);
                }
            }
        }
        __syncthreads();

        // ---- phase B: wave-per-anchor GEMM + relu + maxpool ----
        {
            float4 acc[8][2];   // acc[ocr][qh]: oc = og*8+ocr, q = qg*8+qh*4+comp
#pragma unroll
            for (int i = 0; i < 8; ++i) {
                acc[i][0] = make_float4(0.f, 0.f, 0.f, 0.f);
                acc[i][1] = make_float4(0.f, 0.f, 0.f, 0.f);
            }
            const float* wbase = ws1T + og * 4;
            const float* hbase = &h1T[wa][0][qg * 8];
#define FMA8(ocr, ws) \
    acc[ocr][0].x += ws*h0.x; acc[ocr][0].y += ws*h0.y; acc[ocr][0].z += ws*h0.z; acc[ocr][0].w += ws*h0.w; \
    acc[ocr][1].x += ws*h1.x; acc[ocr][1].y += ws*h1.y; acc[ocr][1].z += ws*h1.z; acc[ocr][1].w += ws*h1.w;
#pragma unroll 4
            for (int k = 0; k < 64; ++k) {
                const float4 h0 = *(const float4*)(hbase + k * 32);
                const float4 h1 = *(const float4*)(hbase + k * 32 + 4);
                const float4 w0 = *(const float4*)(wbase + k * 128);       // oc og*8+0..3
                const float4 w1 = *(const float4*)(wbase + k * 128 + 64);  // oc og*8+4..7
                FMA8(0, w0.x) FMA8(1, w0.y) FMA8(2, w0.z) FMA8(3, w0.w)
                FMA8(4, w1.x) FMA8(5, w1.y) FMA8(6, w1.z) FMA8(7, w1.w)
            }
#undef FMA8
#pragma unroll
            for (int ocr = 0; ocr < 8; ++ocr) {
                float m = fmaxf(
                    fmaxf(fmaxf(acc[ocr][0].x, acc[ocr][0].y), fmaxf(acc[ocr][0].z, acc[ocr][0].w)),
                    fmaxf(fmaxf(acc[ocr][1].x, acc[ocr][1].y), fmaxf(acc[ocr][1].z, acc[ocr][1].w)));
                m = fmaxf(m, __shfl_xor(m, 1));
                m = fmaxf(m, __shfl_xor(m, 2));
                if (qg == 0) hmax[wa][og * 8 + ocr] = fmaxf(m, 0.f);
            }
        }
        __syncthreads();

        // ---- phase C: thread<->oc, st += relu(Wt[j][oc] . hmax[a]) ----
        {
            const float4* wr = (const float4*)(Wt + ((size_t)j << 15) + ((size_t)tid << 7));
            float c0 = 0.f, c1 = 0.f, c2 = 0.f, c3 = 0.f;
#pragma unroll 8
            for (int k4 = 0; k4 < 32; ++k4) {
                const float4 w  = wr[k4];
                const float4 m0 = *(const float4*)&hmax[0][k4 * 4];
                const float4 m1 = *(const float4*)&hmax[1][k4 * 4];
                const float4 m2 = *(const float4*)&hmax[2][k4 * 4];
                const float4 m3 = *(const float4*)&hmax[3][k4 * 4];
                c0 += w.x*m0.x + w.y*m0.y + w.z*m0.z + w.w*m0.w;
                c1 += w.x*m1.x + w.y*m1.y + w.z*m1.z + w.w*m1.w;
                c2 += w.x*m2.x + w.y*m2.y + w.z*m2.z + w.w*m2.w;
                c3 += w.x*m3.x + w.y*m3.y + w.z*m3.z + w.w*m3.w;
            }
            st0 += fmaxf(c0, 0.f);
            st1 += fmaxf(c1, 0.f);
            st2 += fmaxf(c2, 0.f);
            st3 += fmaxf(c3, 0.f);
        }
        // no sync: next-BQ writes only sbidx (prev readers done 2 syncs ago);
        // hmax rewritten only after next post-A sync.
    }

    // thread tid owns output row oc=tid, cols mb*4..+3 -> one float4 store
    *(float4*)(out_feat + ((size_t)bt * 256 + tid) * M_ + mb * 4) =
        make_float4(st0, st1, st2, st3);
}

// ---------------------------------------------------------------------------
extern "C" void kernel_launch(void* const* d_in, const int* in_sizes, int n_in,
                              void* d_out, int out_size, void* d_ws, size_t ws_size,
                              hipStream_t stream) {
    const float* xyzs  = (const float*)d_in[0];   // [4,8,4096,3]
    const float* feats = (const float*)d_in[1];   // [4,8,3,4096]
    const float* Ws0   = (const float*)d_in[2];   // [64,6]
    const float* Ws1   = (const float*)d_in[3];   // [128,64]
    const float* Wt    = (const float*)d_in[4];   // [3,256,128]

    float* out_xyz  = (float*)d_out;              // 4*8*2048*3 floats
    float* out_feat = out_xyz + (size_t)B_ * 8 * M_ * 3;

    (void)d_ws; (void)ws_size;  // workspace-free

    fps_kernel<<<B_ * 8, 512, 0, stream>>>(xyzs, out_xyz);
    mlp_kernel<<<B_ * 8 * (M_ / 4), 256, 0, stream>>>(xyzs, feats, Ws0, Ws1, Wt,
                                                      out_xyz, out_feat);
}